// Round 16
// baseline (441.462 us; speedup 1.0000x reference)
//
#include <hip/hip_runtime.h>
#include <stdint.h>
#include <stddef.h>

#define S_LEN 1024
#define BATCH 8
#define EMB   1024
#define NHEAD 16
#define HDIM  64
#define FDIM  4096
#define NTOK  (S_LEN*BATCH)   // 8192

typedef unsigned short u16s;
typedef __attribute__((ext_vector_type(4))) float  f32x4;
typedef __attribute__((ext_vector_type(8))) u16s   u16x8;
typedef __attribute__((ext_vector_type(4))) u16s   u16x4;
typedef __attribute__((ext_vector_type(8))) __bf16 bf16x8;

__device__ __forceinline__ u16s f2bf(float f) {
  unsigned int x = __float_as_uint(f);
  return (u16s)((x + 0x7FFFu + ((x >> 16) & 1u)) >> 16);
}
__device__ __forceinline__ float bf2f(u16s u) {
  return __uint_as_float((unsigned int)u << 16);
}

__device__ __forceinline__ f32x4 mfma_bf16(u16x8 a, u16x8 b, f32x4 c) {
  return __builtin_amdgcn_mfma_f32_16x16x32_bf16(
      __builtin_bit_cast(bf16x8, a), __builtin_bit_cast(bf16x8, b), c, 0, 0, 0);
}

__device__ __forceinline__ void gload16(const void* g, void* l) {
  __builtin_amdgcn_global_load_lds(
      (const __attribute__((address_space(1))) unsigned int*)g,
      (__attribute__((address_space(3))) unsigned int*)l, 16, 0, 0);
}

// ---------------- fused prep: casts + zproj + bias concat in ONE kernel -----
// blocks 0..21503: fp32->bf16 casts (4 f32/thread):
//   [0,8192) x | [8192,9216) wq | [9216,10240) wk | [10240,11264) wv
//   [11264,12288) wo | [12288,13312) pghw | [13312,17408) fc1w | [17408,21504) fc2w
// blocks 21504..22015: wave-parallel zproj (one wave per output element).
// blocks 22016..22027: qkv bias concat.
__global__ __launch_bounds__(256) void prep_kernel(
    const float* __restrict__ x, const float* __restrict__ wq,
    const float* __restrict__ wk, const float* __restrict__ wv,
    const float* __restrict__ wo, const float* __restrict__ pghw,
    const float* __restrict__ fc1w, const float* __restrict__ fc2w,
    u16s* __restrict__ xb, u16s* __restrict__ bw_qkv, u16s* __restrict__ bw_o,
    u16s* __restrict__ bw_g, u16s* __restrict__ bw_f1, u16s* __restrict__ bw_f2,
    const float* __restrict__ z,
    const float* __restrict__ pgzw, const float* __restrict__ pgzb,
    const float* __restrict__ pvw,  const float* __restrict__ pvb,
    float* __restrict__ zgb, float* __restrict__ zvb,
    const float* __restrict__ bq, const float* __restrict__ bk,
    const float* __restrict__ bv, float* __restrict__ bqkv) {
  const int b = blockIdx.x;
  if (b < 21504) {
    const float* src; u16s* dst; int base;
    if (b < 8192)       { src = x;    dst = xb;                base = 0; }
    else if (b < 9216)  { src = wq;   dst = bw_qkv;            base = 8192; }
    else if (b < 10240) { src = wk;   dst = bw_qkv + 1048576;  base = 9216; }
    else if (b < 11264) { src = wv;   dst = bw_qkv + 2097152;  base = 10240; }
    else if (b < 12288) { src = wo;   dst = bw_o;              base = 11264; }
    else if (b < 13312) { src = pghw; dst = bw_g;              base = 12288; }
    else if (b < 17408) { src = fc1w; dst = bw_f1;             base = 13312; }
    else                { src = fc2w; dst = bw_f2;             base = 17408; }
    const int i = (b - base) * 256 + threadIdx.x;
    float4 v = ((const float4*)src)[i];
    u16x4 o;
    o[0] = f2bf(v.x); o[1] = f2bf(v.y); o[2] = f2bf(v.z); o[3] = f2bf(v.w);
    ((u16x4*)dst)[i] = o;
  } else if (b < 22016) {
    const int blk2 = b - 21504;              // 0..511
    const int wid = threadIdx.x >> 6, lane = threadIdx.x & 63;
    const int idx = blk2 * 4 + wid;          // 0..2047
    const int which = idx >> 10, o = idx & 1023;
    const float* w    = which ? pvw : pgzw;
    const float* bias = which ? pvb : pgzb;
    float* out        = which ? zvb : zgb;
    const float* wr = w + (size_t)o * EMB + lane * 16;
    float wv16[16];
#pragma unroll
    for (int c = 0; c < 4; ++c) {
      float4 t = *(const float4*)(wr + c * 4);
      wv16[c * 4 + 0] = t.x; wv16[c * 4 + 1] = t.y;
      wv16[c * 4 + 2] = t.z; wv16[c * 4 + 3] = t.w;
    }
    float acc[8];
#pragma unroll
    for (int bb = 0; bb < 8; ++bb) {
      const float* zr = z + bb * EMB + lane * 16;
      float s = 0.f;
#pragma unroll
      for (int c = 0; c < 4; ++c) {
        float4 t = *(const float4*)(zr + c * 4);
        s += t.x * wv16[c * 4 + 0] + t.y * wv16[c * 4 + 1] +
             t.z * wv16[c * 4 + 2] + t.w * wv16[c * 4 + 3];
      }
      acc[bb] = s;
    }
#pragma unroll
    for (int m = 1; m < 64; m <<= 1)
#pragma unroll
      for (int bb = 0; bb < 8; ++bb) acc[bb] += __shfl_xor(acc[bb], m);
    if (lane < 8) out[lane * EMB + o] = acc[lane] + bias[o];
  } else {
    const int i = (b - 22016) * 256 + threadIdx.x;   // 0..3071
    bqkv[i] = (i < 1024) ? bq[i] : (i < 2048) ? bk[i - 1024] : bv[i - 2048];
  }
}

// ---------------- LayerNorm (bf16 in) ----------------
template <int MODE>
__global__ __launch_bounds__(256) void ln_kernel(const u16s* __restrict__ y,
                                                 const float* __restrict__ gam,
                                                 const float* __restrict__ bet,
                                                 u16s* __restrict__ obf,
                                                 float* __restrict__ of) {
  const int row = blockIdx.x;
  const int t = threadIdx.x;
  const u16s* yr = y + (size_t)row * EMB;
  u16x4 raw = ((const u16x4*)yr)[t];
  float4 v;
  v.x = bf2f(raw[0]); v.y = bf2f(raw[1]); v.z = bf2f(raw[2]); v.w = bf2f(raw[3]);
  float s = v.x + v.y + v.z + v.w;
  float s2 = v.x * v.x + v.y * v.y + v.z * v.z + v.w * v.w;
#pragma unroll
  for (int m = 1; m < 64; m <<= 1) { s += __shfl_xor(s, m); s2 += __shfl_xor(s2, m); }
  __shared__ float red[8];
  const int wid = t >> 6, lane = t & 63;
  if (lane == 0) { red[wid] = s; red[4 + wid] = s2; }
  __syncthreads();
  s = red[0] + red[1] + red[2] + red[3];
  s2 = red[4] + red[5] + red[6] + red[7];
  float mu = s * (1.f / EMB);
  float var = s2 * (1.f / EMB) - mu * mu;
  float rs = rsqrtf(var + 1e-5f);
  float4 g = ((const float4*)gam)[t];
  float4 b = ((const float4*)bet)[t];
  float4 o;
  o.x = (v.x - mu) * rs * g.x + b.x;
  o.y = (v.y - mu) * rs * g.y + b.y;
  o.z = (v.z - mu) * rs * g.z + b.z;
  o.w = (v.w - mu) * rs * g.w + b.w;
  if constexpr (MODE == 0) {
    u16x4 p;
    p[0] = f2bf(o.x); p[1] = f2bf(o.y); p[2] = f2bf(o.z); p[3] = f2bf(o.w);
    ((u16x4*)(obf + (size_t)row * EMB))[t] = p;
  } else {
    ((float4*)(of + (size_t)row * EMB))[t] = o;
  }
}

enum { EPI_QKV3 = 0, EPI_RELU = 1, EPI_RES = 2, EPI_GATE = 3 };

// ---------------- shared epilogue helper (lane = 1 M-row x 4 N-cols) --------
template <int EPI>
__device__ __forceinline__ void epi_store(f32x4 a, int gr, int gc0, int N,
                                          const float* __restrict__ bias,
                                          u16s* __restrict__ outb,
                                          const u16s* __restrict__ res,
                                          const float* __restrict__ zg,
                                          const float* __restrict__ zv,
                                          float scale) {
  const float4 bv = *(const float4*)(bias + gc0);
  float v0 = a[0] + bv.x, v1 = a[1] + bv.y, v2 = a[2] + bv.z, v3 = a[3] + bv.w;
  if constexpr (EPI == EPI_QKV3) {
    const int which = gc0 >> 10, col0 = gc0 & 1023;
    const int srow = gr >> 3, b = gr & 7, h = col0 >> 6, d0 = col0 & 63;
    if (which == 0) {
      // Q pre-scaled by 1/sqrt(HD) * log2(e): softmax runs in exp2 domain
      u16x4 p; p[0] = f2bf(v0 * scale); p[1] = f2bf(v1 * scale);
      p[2] = f2bf(v2 * scale); p[3] = f2bf(v3 * scale);
      *(u16x4*)(outb + (size_t)(b * 16 + h) * 65536 + srow * 64 + d0) = p;
    } else if (which == 1) {
      u16x4 p; p[0] = f2bf(v0); p[1] = f2bf(v1); p[2] = f2bf(v2); p[3] = f2bf(v3);
      *(u16x4*)(outb + 8388608 + (size_t)(b * 16 + h) * 65536 + srow * 64 + d0) = p;
    } else {
      outb[16777216 + ((size_t)(b * 16 + h) * 64 + d0 + 0) * 1024 + srow] = f2bf(v0);
      outb[16777216 + ((size_t)(b * 16 + h) * 64 + d0 + 1) * 1024 + srow] = f2bf(v1);
      outb[16777216 + ((size_t)(b * 16 + h) * 64 + d0 + 2) * 1024 + srow] = f2bf(v2);
      outb[16777216 + ((size_t)(b * 16 + h) * 64 + d0 + 3) * 1024 + srow] = f2bf(v3);
    }
  } else if constexpr (EPI == EPI_RELU) {
    u16x4 p; p[0] = f2bf(fmaxf(v0, 0.f)); p[1] = f2bf(fmaxf(v1, 0.f));
    p[2] = f2bf(fmaxf(v2, 0.f)); p[3] = f2bf(fmaxf(v3, 0.f));
    *(u16x4*)(outb + (size_t)gr * N + gc0) = p;
  } else if constexpr (EPI == EPI_RES) {
    const u16x4 rr = *(const u16x4*)(res + (size_t)gr * N + gc0);
    u16x4 p; p[0] = f2bf(v0 + bf2f(rr[0])); p[1] = f2bf(v1 + bf2f(rr[1]));
    p[2] = f2bf(v2 + bf2f(rr[2])); p[3] = f2bf(v3 + bf2f(rr[3]));
    *(u16x4*)(outb + (size_t)gr * N + gc0) = p;
  } else {  // EPI_GATE
    const float4 zg4 = *(const float4*)(zg + (gr & 7) * EMB + gc0);
    const float4 zv4 = *(const float4*)(zv + (gr & 7) * EMB + gc0);
    const u16x4 rr = *(const u16x4*)(res + (size_t)gr * EMB + gc0);
    u16x4 p;
    p[0] = f2bf(bf2f(rr[0]) + zv4.x / (1.f + __expf(-(v0 + zg4.x))));
    p[1] = f2bf(bf2f(rr[1]) + zv4.y / (1.f + __expf(-(v1 + zg4.y))));
    p[2] = f2bf(bf2f(rr[2]) + zv4.z / (1.f + __expf(-(v2 + zg4.z))));
    p[3] = f2bf(bf2f(rr[3]) + zv4.w / (1.f + __expf(-(v3 + zg4.w))));
    *(u16x4*)(outb + (size_t)gr * EMB + gc0) = p;
  }
}

// ---------------- GEMM core (R9/R11, FROZEN: fc1 808 TF) --------------------
// 128x128 tile, BK=64, 4 waves (2x2), 32KB LDS, 4 blocks/CU, 16x16x32 MFMA,
// XOR chunk swizzle (conflicts==0), swapped-operand epilogue, bn-FAST grids,
// bijective XCD-CHUNK swizzle. All variants (deep-ring R5/R8, 8-phase R12,
// 32x32 shape R14 -> 8.4M bank conflicts) regressed. Do not touch.
template <int EPI>
__global__ __launch_bounds__(256, 4) void gemm_nt(const u16s* __restrict__ A,
                                                  const u16s* __restrict__ Bw,
                                                  const float* __restrict__ bias,
                                                  void* __restrict__ out,
                                                  const u16s* __restrict__ res,
                                                  const float* __restrict__ zg,
                                                  const float* __restrict__ zv,
                                                  int M, int N, int K, float scale) {
  __shared__ u16s As[128 * 64];
  __shared__ u16s Bs[128 * 64];
  const int tid = threadIdx.x;
  const int wid = tid >> 6, lane = tid & 63;
  const int wm = wid >> 1, wn = wid & 1;
  const int l15 = lane & 15, l4 = lane >> 4;

  const int nwg = gridDim.x * gridDim.y;
  int lin = blockIdx.y * gridDim.x + blockIdx.x;
  lin = (lin & 7) * (nwg >> 3) + (lin >> 3);
  const int bn0 = (lin % gridDim.x) * 128;
  const int bm0 = (lin / gridDim.x) * 128;

  const int wbase = tid & ~63;
  int srowA[4], scolA[4];
#pragma unroll
  for (int ii = 0; ii < 4; ++ii) {
    const int ell = ii * 256 + tid;
    const int row = ell >> 3;
    srowA[ii] = row;
    scolA[ii] = ((ell & 7) ^ (row & 7)) * 8;
  }

  f32x4 acc[4][4] = {};
  const int nkt = K >> 6;
  for (int kt = 0; kt < nkt; ++kt) {
#pragma unroll
    for (int ii = 0; ii < 4; ++ii) {
      gload16(A + (size_t)(bm0 + srowA[ii]) * K + kt * 64 + scolA[ii],
              As + (size_t)(ii * 256 + wbase) * 8);
      gload16(Bw + (size_t)(bn0 + srowA[ii]) * K + kt * 64 + scolA[ii],
              Bs + (size_t)(ii * 256 + wbase) * 8);
    }
    __syncthreads();
#pragma unroll
    for (int kk = 0; kk < 2; ++kk) {
      const int cs = kk * 4 + l4;
      u16x8 af[4], bfr[4];
#pragma unroll
      for (int i = 0; i < 4; ++i) {
        const int row = wm * 64 + i * 16 + l15;
        af[i] = *(const u16x8*)(As + row * 64 + (cs ^ (l15 & 7)) * 8);
      }
#pragma unroll
      for (int j = 0; j < 4; ++j) {
        const int row = wn * 64 + j * 16 + l15;
        bfr[j] = *(const u16x8*)(Bs + row * 64 + (cs ^ (l15 & 7)) * 8);
      }
      __builtin_amdgcn_s_setprio(1);
#pragma unroll
      for (int i = 0; i < 4; ++i)
#pragma unroll
        for (int j = 0; j < 4; ++j)
          acc[i][j] = mfma_bf16(bfr[j], af[i], acc[i][j]);
      __builtin_amdgcn_s_setprio(0);
    }
    __syncthreads();
  }

  u16s* outb = (u16s*)out;
#pragma unroll
  for (int i = 0; i < 4; ++i) {
    const int gr = bm0 + wm * 64 + i * 16 + l15;
#pragma unroll
    for (int j = 0; j < 4; ++j) {
      const int gc0 = bn0 + wn * 64 + j * 16 + l4 * 4;
      epi_store<EPI>(acc[i][j], gr, gc0, N, bias, outb, res, zg, zv, scale);
    }
  }
}

// ---------------- causal flash attention (KVBLK=64, exp2 softmax) -----------
// grid: (8 qt-pairs, 128 (b,h)); block p handles q-tiles {p, 15-p}
// sequentially. Q pre-scaled by log2(e)/sqrt(HD) -> scores in log2 domain,
// exp2f everywhere (saves the v_mul inside each __expf). Causal masking only
// on the diagonal tile (kt==qt); defer-max THR = 8*log2e (P bound e^8).
__global__ __launch_bounds__(256, 4) void attn_kernel(const u16s* __restrict__ Q,
                                                      const u16s* __restrict__ K,
                                                      const u16s* __restrict__ VT,
                                                      u16s* __restrict__ O) {
  __shared__ u16s Ks[64 * 72];
  __shared__ u16s Vs[64 * 72];
  __shared__ u16s Pl[4][16 * 72];
  const int p = blockIdx.x, bh = blockIdx.y;
  const int tid = threadIdx.x;
  const int wid = tid >> 6, lane = tid & 63;
  const int l15 = lane & 15, l4 = lane >> 4;
  const size_t hoff = (size_t)bh * (S_LEN * HDIM);
  const u16s* Qb = Q + hoff;
  const u16s* Kb = K + hoff;   // [1024 s][64 d]
  const u16s* Vb = VT + hoff;  // [64 d][1024 s]
  u16s* Pw = Pl[wid];
  const int b = bh >> 4, h = bh & 15;

  int srow[2], scol[2];
#pragma unroll
  for (int i = 0; i < 2; ++i) {
    const int ell = i * 256 + tid;
    srow[i] = ell >> 3;
    scol[i] = (ell & 7) * 8;
  }

  for (int half = 0; half < 2; ++half) {
    const int qt = half ? (15 - p) : p;
    const int qrow = qt * 64 + wid * 16 + l15;
    const u16x8 qf0 = *(const u16x8*)(Qb + qrow * 64 + l4 * 8);
    const u16x8 qf1 = *(const u16x8*)(Qb + qrow * 64 + 32 + l4 * 8);
    f32x4 oa[4] = {};
    float mrun = -1e30f, lsum = 0.f;
    const int nkt = qt + 1;

    u16x8 kreg[2], vreg[2];
#pragma unroll
    for (int i = 0; i < 2; ++i) {
      kreg[i] = *(const u16x8*)(Kb + (size_t)srow[i] * 64 + scol[i]);
      vreg[i] = *(const u16x8*)(Vb + (size_t)srow[i] * 1024 + scol[i]);
    }

    for (int kt = 0; kt < nkt; ++kt) {
      __syncthreads();
#pragma unroll
      for (int i = 0; i < 2; ++i) {
        *(u16x8*)(Ks + srow[i] * 72 + scol[i]) = kreg[i];
        *(u16x8*)(Vs + srow[i] * 72 + scol[i]) = vreg[i];
      }
      __syncthreads();
      if (kt + 1 < nkt) {
#pragma unroll
        for (int i = 0; i < 2; ++i) {
          kreg[i] = *(const u16x8*)(Kb + (size_t)((kt + 1) * 64 + srow[i]) * 64 + scol[i]);
          vreg[i] = *(const u16x8*)(Vb + (size_t)srow[i] * 1024 + (kt + 1) * 64 + scol[i]);
        }
      }
      f32x4 sc[4] = {};
      {
        u16x8 kfA[4], kfB[4];
#pragma unroll
        for (int g = 0; g < 4; ++g) {
          kfA[g] = *(const u16x8*)(Ks + (g * 16 + l15) * 72 + l4 * 8);
          kfB[g] = *(const u16x8*)(Ks + (g * 16 + l15) * 72 + 32 + l4 * 8);
        }
        __builtin_amdgcn_s_setprio(1);
#pragma unroll
        for (int g = 0; g < 4; ++g) {
          sc[g] = mfma_bf16(kfA[g], qf0, sc[g]);
          sc[g] = mfma_bf16(kfB[g], qf1, sc[g]);
        }
        __builtin_amdgcn_s_setprio(0);
      }
      u16x8 vf0[4], vf1[4];
#pragma unroll
      for (int df = 0; df < 4; ++df) {
        vf0[df] = *(const u16x8*)(Vs + (df * 16 + l15) * 72 + l4 * 8);
        vf1[df] = *(const u16x8*)(Vs + (df * 16 + l15) * 72 + 32 + l4 * 8);
      }

      float sv[16];
      float pmax = -1e30f;
      if (kt == qt) {   // diagonal tile: apply causal mask (block-uniform)
        const int kbase = kt * 64;
#pragma unroll
        for (int g = 0; g < 4; ++g)
#pragma unroll
          for (int r = 0; r < 4; ++r) {
            const int kg = kbase + g * 16 + l4 * 4 + r;
            const float s0 = (kg <= qrow) ? sc[g][r] : -1e9f;
            sv[g * 4 + r] = s0;
            pmax = fmaxf(pmax, s0);
          }
      } else {          // strictly-below-diagonal: no mask needed
#pragma unroll
        for (int g = 0; g < 4; ++g)
#pragma unroll
          for (int r = 0; r < 4; ++r) {
            const float s0 = sc[g][r];
            sv[g * 4 + r] = s0;
            pmax = fmaxf(pmax, s0);
          }
      }
      pmax = fmaxf(pmax, __shfl_xor(pmax, 16));
      pmax = fmaxf(pmax, __shfl_xor(pmax, 32));
      // defer-max in log2 domain: THR = 8 * log2(e) -> P bounded by e^8
      if (!__all(pmax <= mrun + 11.5442f)) {
        const float mnew = fmaxf(mrun, pmax);
        const float fsc = exp2f(mrun - mnew);
        lsum *= fsc;
#pragma unroll
        for (int df = 0; df < 4; ++df) oa[df] *= fsc;
        mrun = mnew;
      }
      float psum = 0.f;
#pragma unroll
      for (int i = 0; i < 16; ++i) { float pv = exp2f(sv[i] - mrun); sv[i] = pv; psum += pv; }
      psum += __shfl_xor(psum, 16);
      psum += __shfl_xor(psum, 32);
      lsum += psum;

#pragma unroll
      for (int g = 0; g < 4; ++g) {
        u16x4 pk;
#pragma unroll
        for (int r = 0; r < 4; ++r) pk[r] = f2bf(sv[g * 4 + r]);
        *(u16x4*)(Pw + l15 * 72 + g * 16 + l4 * 4) = pk;
      }
      asm volatile("s_waitcnt lgkmcnt(0)" ::: "memory");
      const u16x8 pf0 = *(const u16x8*)(Pw + l15 * 72 + l4 * 8);
      const u16x8 pf1 = *(const u16x8*)(Pw + l15 * 72 + 32 + l4 * 8);
      __builtin_amdgcn_s_setprio(1);
#pragma unroll
      for (int df = 0; df < 4; ++df) {
        oa[df] = mfma_bf16(vf0[df], pf0, oa[df]);
        oa[df] = mfma_bf16(vf1[df], pf1, oa[df]);
      }
      __builtin_amdgcn_s_setprio(0);
    }
    const float inv = 1.f / lsum;
    u16s* orow = O + ((size_t)qrow * 8 + b) * EMB + h * 64;
#pragma unroll
    for (int df = 0; df < 4; ++df)
#pragma unroll
      for (int r = 0; r < 4; ++r)
        orow[df * 16 + l4 * 4 + r] = f2bf(oa[df][r] * inv);
  }
}

// ---------------- driver ----------------
extern "C" void kernel_launch(void* const* d_in, const int* in_sizes, int n_in,
                              void* d_out, int out_size, void* d_ws, size_t ws_size,
                              hipStream_t stream) {
  const float* x = (const float*)d_in[0];
  const float* z = (const float*)d_in[1];
  const float* wq = (const float*)d_in[2];  const float* bq = (const float*)d_in[3];
  const float* wk = (const float*)d_in[4];  const float* bk = (const float*)d_in[5];
  const float* wv = (const float*)d_in[6];  const float* bv = (const float*)d_in[7];
  const float* wo = (const float*)d_in[8];  const float* bo = (const float*)d_in[9];
  const float* ln1g = (const float*)d_in[10]; const float* ln1b = (const float*)d_in[11];
  const float* pghw = (const float*)d_in[12]; const float* pghb = (const float*)d_in[13];
  const float* pgzw = (const float*)d_in[14]; const float* pgzb = (const float*)d_in[15];
  const float* pvw  = (const float*)d_in[16]; const float* pvb  = (const float*)d_in[17];
  const float* ln2g = (const float*)d_in[18]; const float* ln2b = (const float*)d_in[19];
  const float* fc1w = (const float*)d_in[20]; const float* fc1b = (const float*)d_in[21];
  const float* fc2w = (const float*)d_in[22]; const float* fc2b = (const float*)d_in[23];
  const float* ln3g = (const float*)d_in[24]; const float* ln3b = (const float*)d_in[25];

  char* ws = (char*)d_ws;
  size_t off = 0;
  auto alloc = [&](size_t bytes) -> char* {
    char* p = ws + off;
    off += (bytes + 255) & ~(size_t)255;
    return p;
  };

  u16s* bw_qkv = (u16s*)alloc(2u * 3145728);  // wq|wk|wv concat (3072x1024)
  u16s* bw_o = (u16s*)alloc(2u * 1048576);
  u16s* bw_g = (u16s*)alloc(2u * 1048576);
  u16s* bw_f1 = (u16s*)alloc(2u * 4194304);
  u16s* bw_f2 = (u16s*)alloc(2u * 4194304);
  u16s* xb = (u16s*)alloc(2u * 8388608);
  // qh, kh, vT, attnb are four contiguous 16MB buffers (the QKV3 epilogue
  // relies on qh+8388608 == kh, qh+16777216 == vT); hbuf (8192x4096 bf16 =
  // 64MB) aliases all four. vT is V pre-transposed per head: vT[bh][64][1024].
  u16s* qh = (u16s*)alloc(2u * 8388608);
  u16s* kh = (u16s*)alloc(2u * 8388608);
  u16s* vT = (u16s*)alloc(2u * 8388608);
  u16s* attnb = (u16s*)alloc(2u * 8388608);
  u16s* hbuf = qh;
  u16s* ybufb = (u16s*)alloc(2u * 8388608);   // bf16 pre-LN buffer
  u16s* x1b = (u16s*)alloc(2u * 8388608);     // LN1 output (bf16)
  u16s* x2b = (u16s*)alloc(2u * 8388608);     // LN2 output (bf16)
  float* zgb = (float*)alloc(4u * 8192);
  float* zvb = (float*)alloc(4u * 8192);
  float* bqkv = (float*)alloc(4u * 3072);
  (void)off; (void)ws_size; (void)in_sizes; (void)n_in; (void)out_size;
  (void)kh; (void)vT;

  // fused prep: casts + zproj + bias concat, one launch
  prep_kernel<<<22028, 256, 0, stream>>>(x, wq, wk, wv, wo, pghw, fc1w, fc2w,
                                         xb, bw_qkv, bw_o, bw_g, bw_f1, bw_f2,
                                         z, pgzw, pgzb, pvw, pvb, zgb, zvb,
                                         bq, bk, bv, bqkv);

  // fused QKV projection (N=3072); Q scale folded with log2(e) for exp2 softmax
  gemm_nt<EPI_QKV3><<<dim3(24, 64), 256, 0, stream>>>(
      xb, bw_qkv, bqkv, qh, nullptr, nullptr, nullptr, NTOK, 3072, EMB,
      0.125f * 1.44269504f);

  attn_kernel<<<dim3(8, 128), 256, 0, stream>>>(qh, kh, vT, attnb);

  // out-proj + residual(xb) -> ybufb (bf16), then LN1 -> x1b
  gemm_nt<EPI_RES><<<dim3(8, 64), 256, 0, stream>>>(
      attnb, bw_o, bo, ybufb, xb, nullptr, nullptr, NTOK, EMB, EMB, 1.f);
  ln_kernel<0><<<NTOK, 256, 0, stream>>>(ybufb, ln1g, ln1b, x1b, nullptr);

  // gated fusion (residual x1b) -> ybufb, then LN2 -> x2b
  gemm_nt<EPI_GATE><<<dim3(8, 64), 256, 0, stream>>>(
      x1b, bw_g, pghb, ybufb, x1b, zgb, zvb, NTOK, EMB, EMB, 1.f);
  ln_kernel<0><<<NTOK, 256, 0, stream>>>(ybufb, ln2g, ln2b, x2b, nullptr);

  // FFN (residual x2b) -> ybufb, then LN3 -> d_out (f32)
  gemm_nt<EPI_RELU><<<dim3(32, 64), 256, 0, stream>>>(
      x2b, bw_f1, fc1b, hbuf, nullptr, nullptr, nullptr, NTOK, FDIM, EMB, 1.f);
  gemm_nt<EPI_RES><<<dim3(8, 64), 256, 0, stream>>>(
      hbuf, bw_f2, fc2b, ybufb, x2b, nullptr, nullptr, NTOK, EMB, FDIM, 1.f);
  ln_kernel<1><<<NTOK, 256, 0, stream>>>(ybufb, ln3g, ln3b, nullptr, (float*)d_out);
}

// Round 17
// 434.722 us; speedup vs baseline: 1.0155x; 1.0155x over previous
//
#include <hip/hip_runtime.h>
#include <stdint.h>
#include <stddef.h>

#define S_LEN 1024
#define BATCH 8
#define EMB   1024
#define NHEAD 16
#define HDIM  64
#define FDIM  4096
#define NTOK  (S_LEN*BATCH)   // 8192

typedef unsigned short u16s;
typedef __attribute__((ext_vector_type(4))) float  f32x4;
typedef __attribute__((ext_vector_type(8))) u16s   u16x8;
typedef __attribute__((ext_vector_type(4))) u16s   u16x4;
typedef __attribute__((ext_vector_type(8))) __bf16 bf16x8;

__device__ __forceinline__ u16s f2bf(float f) {
  unsigned int x = __float_as_uint(f);
  return (u16s)((x + 0x7FFFu + ((x >> 16) & 1u)) >> 16);
}
__device__ __forceinline__ float bf2f(u16s u) {
  return __uint_as_float((unsigned int)u << 16);
}

__device__ __forceinline__ f32x4 mfma_bf16(u16x8 a, u16x8 b, f32x4 c) {
  return __builtin_amdgcn_mfma_f32_16x16x32_bf16(
      __builtin_bit_cast(bf16x8, a), __builtin_bit_cast(bf16x8, b), c, 0, 0, 0);
}

__device__ __forceinline__ void gload16(const void* g, void* l) {
  __builtin_amdgcn_global_load_lds(
      (const __attribute__((address_space(1))) unsigned int*)g,
      (__attribute__((address_space(3))) unsigned int*)l, 16, 0, 0);
}

// ---------------- fused prep: all fp32->bf16 casts in ONE kernel ------------
// (R16 tried merging small_kernel into this launch: the 524-block tail ran
// after the 21504 cast blocks drained and QKV3 idled 141us at 0.2% MfmaUtil.
// Keep the two launches SEPARATE so the small kernel overlaps the cast tail.)
__global__ __launch_bounds__(256) void prep_kernel(
    const float* __restrict__ x, const float* __restrict__ wq,
    const float* __restrict__ wk, const float* __restrict__ wv,
    const float* __restrict__ wo, const float* __restrict__ pghw,
    const float* __restrict__ fc1w, const float* __restrict__ fc2w,
    u16s* __restrict__ xb, u16s* __restrict__ bw_qkv, u16s* __restrict__ bw_o,
    u16s* __restrict__ bw_g, u16s* __restrict__ bw_f1, u16s* __restrict__ bw_f2) {
  const int b = blockIdx.x;
  const float* src; u16s* dst; int base;
  if (b < 8192)       { src = x;    dst = xb;                base = 0; }
  else if (b < 9216)  { src = wq;   dst = bw_qkv;            base = 8192; }
  else if (b < 10240) { src = wk;   dst = bw_qkv + 1048576;  base = 9216; }
  else if (b < 11264) { src = wv;   dst = bw_qkv + 2097152;  base = 10240; }
  else if (b < 12288) { src = wo;   dst = bw_o;              base = 11264; }
  else if (b < 13312) { src = pghw; dst = bw_g;              base = 12288; }
  else if (b < 17408) { src = fc1w; dst = bw_f1;             base = 13312; }
  else                { src = fc2w; dst = bw_f2;             base = 17408; }
  const int i = (b - base) * 256 + threadIdx.x;
  float4 v = ((const float4*)src)[i];
  u16x4 o;
  o[0] = f2bf(v.x); o[1] = f2bf(v.y); o[2] = f2bf(v.z); o[3] = f2bf(v.w);
  ((u16x4*)dst)[i] = o;
}

// ---------------- fused small kernel: wave-parallel zproj + bias concat -----
__global__ __launch_bounds__(256) void small_kernel(
    const float* __restrict__ z,
    const float* __restrict__ pgzw, const float* __restrict__ pgzb,
    const float* __restrict__ pvw,  const float* __restrict__ pvb,
    float* __restrict__ zgb, float* __restrict__ zvb,
    const float* __restrict__ bq, const float* __restrict__ bk,
    const float* __restrict__ bv, float* __restrict__ bqkv) {
  const int blk = blockIdx.x;
  if (blk < 512) {
    const int wid = threadIdx.x >> 6, lane = threadIdx.x & 63;
    const int idx = blk * 4 + wid;           // 0..2047
    const int which = idx >> 10, o = idx & 1023;
    const float* w    = which ? pvw : pgzw;
    const float* bias = which ? pvb : pgzb;
    float* out        = which ? zvb : zgb;
    const float* wr = w + (size_t)o * EMB + lane * 16;
    float wv[16];
#pragma unroll
    for (int c = 0; c < 4; ++c) {
      float4 t = *(const float4*)(wr + c * 4);
      wv[c * 4 + 0] = t.x; wv[c * 4 + 1] = t.y; wv[c * 4 + 2] = t.z; wv[c * 4 + 3] = t.w;
    }
    float acc[8];
#pragma unroll
    for (int b = 0; b < 8; ++b) {
      const float* zr = z + b * EMB + lane * 16;
      float s = 0.f;
#pragma unroll
      for (int c = 0; c < 4; ++c) {
        float4 t = *(const float4*)(zr + c * 4);
        s += t.x * wv[c * 4 + 0] + t.y * wv[c * 4 + 1] +
             t.z * wv[c * 4 + 2] + t.w * wv[c * 4 + 3];
      }
      acc[b] = s;
    }
#pragma unroll
    for (int m = 1; m < 64; m <<= 1)
#pragma unroll
      for (int b = 0; b < 8; ++b) acc[b] += __shfl_xor(acc[b], m);
    if (lane < 8) out[lane * EMB + o] = acc[lane] + bias[o];
  } else {
    const int i = (blk - 512) * 256 + threadIdx.x;   // 0..3071
    bqkv[i] = (i < 1024) ? bq[i] : (i < 2048) ? bk[i - 1024] : bv[i - 2048];
  }
}

// ---------------- LayerNorm (bf16 in) ----------------
template <int MODE>
__global__ __launch_bounds__(256) void ln_kernel(const u16s* __restrict__ y,
                                                 const float* __restrict__ gam,
                                                 const float* __restrict__ bet,
                                                 u16s* __restrict__ obf,
                                                 float* __restrict__ of) {
  const int row = blockIdx.x;
  const int t = threadIdx.x;
  const u16s* yr = y + (size_t)row * EMB;
  u16x4 raw = ((const u16x4*)yr)[t];
  float4 v;
  v.x = bf2f(raw[0]); v.y = bf2f(raw[1]); v.z = bf2f(raw[2]); v.w = bf2f(raw[3]);
  float s = v.x + v.y + v.z + v.w;
  float s2 = v.x * v.x + v.y * v.y + v.z * v.z + v.w * v.w;
#pragma unroll
  for (int m = 1; m < 64; m <<= 1) { s += __shfl_xor(s, m); s2 += __shfl_xor(s2, m); }
  __shared__ float red[8];
  const int wid = t >> 6, lane = t & 63;
  if (lane == 0) { red[wid] = s; red[4 + wid] = s2; }
  __syncthreads();
  s = red[0] + red[1] + red[2] + red[3];
  s2 = red[4] + red[5] + red[6] + red[7];
  float mu = s * (1.f / EMB);
  float var = s2 * (1.f / EMB) - mu * mu;
  float rs = rsqrtf(var + 1e-5f);
  float4 g = ((const float4*)gam)[t];
  float4 b = ((const float4*)bet)[t];
  float4 o;
  o.x = (v.x - mu) * rs * g.x + b.x;
  o.y = (v.y - mu) * rs * g.y + b.y;
  o.z = (v.z - mu) * rs * g.z + b.z;
  o.w = (v.w - mu) * rs * g.w + b.w;
  if constexpr (MODE == 0) {
    u16x4 p;
    p[0] = f2bf(o.x); p[1] = f2bf(o.y); p[2] = f2bf(o.z); p[3] = f2bf(o.w);
    ((u16x4*)(obf + (size_t)row * EMB))[t] = p;
  } else {
    ((float4*)(of + (size_t)row * EMB))[t] = o;
  }
}

enum { EPI_QKV3 = 0, EPI_RELU = 1, EPI_RES = 2, EPI_GATE = 3 };

// ---------------- shared epilogue helper (lane = 1 M-row x 4 N-cols) --------
template <int EPI>
__device__ __forceinline__ void epi_store(f32x4 a, int gr, int gc0, int N,
                                          const float* __restrict__ bias,
                                          u16s* __restrict__ outb,
                                          const u16s* __restrict__ res,
                                          const float* __restrict__ zg,
                                          const float* __restrict__ zv,
                                          float scale) {
  const float4 bv = *(const float4*)(bias + gc0);
  float v0 = a[0] + bv.x, v1 = a[1] + bv.y, v2 = a[2] + bv.z, v3 = a[3] + bv.w;
  if constexpr (EPI == EPI_QKV3) {
    const int which = gc0 >> 10, col0 = gc0 & 1023;
    const int srow = gr >> 3, b = gr & 7, h = col0 >> 6, d0 = col0 & 63;
    if (which == 0) {
      u16x4 p; p[0] = f2bf(v0 * scale); p[1] = f2bf(v1 * scale);
      p[2] = f2bf(v2 * scale); p[3] = f2bf(v3 * scale);
      *(u16x4*)(outb + (size_t)(b * 16 + h) * 65536 + srow * 64 + d0) = p;
    } else if (which == 1) {
      u16x4 p; p[0] = f2bf(v0); p[1] = f2bf(v1); p[2] = f2bf(v2); p[3] = f2bf(v3);
      *(u16x4*)(outb + 8388608 + (size_t)(b * 16 + h) * 65536 + srow * 64 + d0) = p;
    } else {
      outb[16777216 + ((size_t)(b * 16 + h) * 64 + d0 + 0) * 1024 + srow] = f2bf(v0);
      outb[16777216 + ((size_t)(b * 16 + h) * 64 + d0 + 1) * 1024 + srow] = f2bf(v1);
      outb[16777216 + ((size_t)(b * 16 + h) * 64 + d0 + 2) * 1024 + srow] = f2bf(v2);
      outb[16777216 + ((size_t)(b * 16 + h) * 64 + d0 + 3) * 1024 + srow] = f2bf(v3);
    }
  } else if constexpr (EPI == EPI_RELU) {
    u16x4 p; p[0] = f2bf(fmaxf(v0, 0.f)); p[1] = f2bf(fmaxf(v1, 0.f));
    p[2] = f2bf(fmaxf(v2, 0.f)); p[3] = f2bf(fmaxf(v3, 0.f));
    *(u16x4*)(outb + (size_t)gr * N + gc0) = p;
  } else if constexpr (EPI == EPI_RES) {
    const u16x4 rr = *(const u16x4*)(res + (size_t)gr * N + gc0);
    u16x4 p; p[0] = f2bf(v0 + bf2f(rr[0])); p[1] = f2bf(v1 + bf2f(rr[1]));
    p[2] = f2bf(v2 + bf2f(rr[2])); p[3] = f2bf(v3 + bf2f(rr[3]));
    *(u16x4*)(outb + (size_t)gr * N + gc0) = p;
  } else {  // EPI_GATE
    const float4 zg4 = *(const float4*)(zg + (gr & 7) * EMB + gc0);
    const float4 zv4 = *(const float4*)(zv + (gr & 7) * EMB + gc0);
    const u16x4 rr = *(const u16x4*)(res + (size_t)gr * EMB + gc0);
    u16x4 p;
    p[0] = f2bf(bf2f(rr[0]) + zv4.x / (1.f + __expf(-(v0 + zg4.x))));
    p[1] = f2bf(bf2f(rr[1]) + zv4.y / (1.f + __expf(-(v1 + zg4.y))));
    p[2] = f2bf(bf2f(rr[2]) + zv4.z / (1.f + __expf(-(v2 + zg4.z))));
    p[3] = f2bf(bf2f(rr[3]) + zv4.w / (1.f + __expf(-(v3 + zg4.w))));
    *(u16x4*)(outb + (size_t)gr * EMB + gc0) = p;
  }
}

// ---------------- GEMM core (R9/R11, FROZEN: fc1 808 TF) --------------------
// 128x128 tile, BK=64, 4 waves (2x2), 32KB LDS, 4 blocks/CU, 16x16x32 MFMA,
// XOR chunk swizzle (conflicts==0), swapped-operand epilogue, bn-FAST grids,
// bijective XCD-CHUNK swizzle. All variants (deep-ring R5/R8, 8-phase R12,
// 32x32 shape R14 -> 8.4M bank conflicts) regressed. Do not touch.
template <int EPI>
__global__ __launch_bounds__(256, 4) void gemm_nt(const u16s* __restrict__ A,
                                                  const u16s* __restrict__ Bw,
                                                  const float* __restrict__ bias,
                                                  void* __restrict__ out,
                                                  const u16s* __restrict__ res,
                                                  const float* __restrict__ zg,
                                                  const float* __restrict__ zv,
                                                  int M, int N, int K, float scale) {
  __shared__ u16s As[128 * 64];
  __shared__ u16s Bs[128 * 64];
  const int tid = threadIdx.x;
  const int wid = tid >> 6, lane = tid & 63;
  const int wm = wid >> 1, wn = wid & 1;
  const int l15 = lane & 15, l4 = lane >> 4;

  const int nwg = gridDim.x * gridDim.y;
  int lin = blockIdx.y * gridDim.x + blockIdx.x;
  lin = (lin & 7) * (nwg >> 3) + (lin >> 3);
  const int bn0 = (lin % gridDim.x) * 128;
  const int bm0 = (lin / gridDim.x) * 128;

  const int wbase = tid & ~63;
  int srowA[4], scolA[4];
#pragma unroll
  for (int ii = 0; ii < 4; ++ii) {
    const int ell = ii * 256 + tid;
    const int row = ell >> 3;
    srowA[ii] = row;
    scolA[ii] = ((ell & 7) ^ (row & 7)) * 8;
  }

  f32x4 acc[4][4] = {};
  const int nkt = K >> 6;
  for (int kt = 0; kt < nkt; ++kt) {
#pragma unroll
    for (int ii = 0; ii < 4; ++ii) {
      gload16(A + (size_t)(bm0 + srowA[ii]) * K + kt * 64 + scolA[ii],
              As + (size_t)(ii * 256 + wbase) * 8);
      gload16(Bw + (size_t)(bn0 + srowA[ii]) * K + kt * 64 + scolA[ii],
              Bs + (size_t)(ii * 256 + wbase) * 8);
    }
    __syncthreads();
#pragma unroll
    for (int kk = 0; kk < 2; ++kk) {
      const int cs = kk * 4 + l4;
      u16x8 af[4], bfr[4];
#pragma unroll
      for (int i = 0; i < 4; ++i) {
        const int row = wm * 64 + i * 16 + l15;
        af[i] = *(const u16x8*)(As + row * 64 + (cs ^ (l15 & 7)) * 8);
      }
#pragma unroll
      for (int j = 0; j < 4; ++j) {
        const int row = wn * 64 + j * 16 + l15;
        bfr[j] = *(const u16x8*)(Bs + row * 64 + (cs ^ (l15 & 7)) * 8);
      }
      __builtin_amdgcn_s_setprio(1);
#pragma unroll
      for (int i = 0; i < 4; ++i)
#pragma unroll
        for (int j = 0; j < 4; ++j)
          acc[i][j] = mfma_bf16(bfr[j], af[i], acc[i][j]);
      __builtin_amdgcn_s_setprio(0);
    }
    __syncthreads();
  }

  u16s* outb = (u16s*)out;
#pragma unroll
  for (int i = 0; i < 4; ++i) {
    const int gr = bm0 + wm * 64 + i * 16 + l15;
#pragma unroll
    for (int j = 0; j < 4; ++j) {
      const int gc0 = bn0 + wn * 64 + j * 16 + l4 * 4;
      epi_store<EPI>(acc[i][j], gr, gc0, N, bias, outb, res, zg, zv, scale);
    }
  }
}

// ---------------- causal flash attention (KVBLK=64, lean softmax) -----------
// grid: (8 qt-pairs, 128 (b,h)); block p handles q-tiles {p, 15-p}
// sequentially. Causal masking only on the DIAGONAL tile (kt == qt);
// defer-max (T13, THR=8): skip the rescale when __all(pmax <= mrun + 8) --
// P bounded by e^8, safe in bf16. (R16's exp2-domain variant was neutral;
// reverted to __expf.)
__global__ __launch_bounds__(256) void attn_kernel(const u16s* __restrict__ Q,
                                                   const u16s* __restrict__ K,
                                                   const u16s* __restrict__ VT,
                                                   u16s* __restrict__ O) {
  __shared__ u16s Ks[64 * 72];
  __shared__ u16s Vs[64 * 72];
  __shared__ u16s Pl[4][16 * 72];
  const int p = blockIdx.x, bh = blockIdx.y;
  const int tid = threadIdx.x;
  const int wid = tid >> 6, lane = tid & 63;
  const int l15 = lane & 15, l4 = lane >> 4;
  const size_t hoff = (size_t)bh * (S_LEN * HDIM);
  const u16s* Qb = Q + hoff;
  const u16s* Kb = K + hoff;   // [1024 s][64 d]
  const u16s* Vb = VT + hoff;  // [64 d][1024 s]
  u16s* Pw = Pl[wid];
  const int b = bh >> 4, h = bh & 15;

  int srow[2], scol[2];
#pragma unroll
  for (int i = 0; i < 2; ++i) {
    const int ell = i * 256 + tid;
    srow[i] = ell >> 3;
    scol[i] = (ell & 7) * 8;
  }

  for (int half = 0; half < 2; ++half) {
    const int qt = half ? (15 - p) : p;
    const int qrow = qt * 64 + wid * 16 + l15;
    const u16x8 qf0 = *(const u16x8*)(Qb + qrow * 64 + l4 * 8);
    const u16x8 qf1 = *(const u16x8*)(Qb + qrow * 64 + 32 + l4 * 8);
    f32x4 oa[4] = {};
    float mrun = -1e30f, lsum = 0.f;
    const int nkt = qt + 1;

    u16x8 kreg[2], vreg[2];
#pragma unroll
    for (int i = 0; i < 2; ++i) {
      kreg[i] = *(const u16x8*)(Kb + (size_t)srow[i] * 64 + scol[i]);
      vreg[i] = *(const u16x8*)(Vb + (size_t)srow[i] * 1024 + scol[i]);
    }

    for (int kt = 0; kt < nkt; ++kt) {
      __syncthreads();
#pragma unroll
      for (int i = 0; i < 2; ++i) {
        *(u16x8*)(Ks + srow[i] * 72 + scol[i]) = kreg[i];
        *(u16x8*)(Vs + srow[i] * 72 + scol[i]) = vreg[i];
      }
      __syncthreads();
      if (kt + 1 < nkt) {
#pragma unroll
        for (int i = 0; i < 2; ++i) {
          kreg[i] = *(const u16x8*)(Kb + (size_t)((kt + 1) * 64 + srow[i]) * 64 + scol[i]);
          vreg[i] = *(const u16x8*)(Vb + (size_t)srow[i] * 1024 + (kt + 1) * 64 + scol[i]);
        }
      }
      f32x4 sc[4] = {};
      {
        u16x8 kfA[4], kfB[4];
#pragma unroll
        for (int g = 0; g < 4; ++g) {
          kfA[g] = *(const u16x8*)(Ks + (g * 16 + l15) * 72 + l4 * 8);
          kfB[g] = *(const u16x8*)(Ks + (g * 16 + l15) * 72 + 32 + l4 * 8);
        }
        __builtin_amdgcn_s_setprio(1);
#pragma unroll
        for (int g = 0; g < 4; ++g) {
          sc[g] = mfma_bf16(kfA[g], qf0, sc[g]);
          sc[g] = mfma_bf16(kfB[g], qf1, sc[g]);
        }
        __builtin_amdgcn_s_setprio(0);
      }
      u16x8 vf0[4], vf1[4];
#pragma unroll
      for (int df = 0; df < 4; ++df) {
        vf0[df] = *(const u16x8*)(Vs + (df * 16 + l15) * 72 + l4 * 8);
        vf1[df] = *(const u16x8*)(Vs + (df * 16 + l15) * 72 + 32 + l4 * 8);
      }

      float sv[16];
      float pmax = -1e30f;
      if (kt == qt) {   // diagonal tile: apply causal mask (block-uniform)
        const int kbase = kt * 64;
#pragma unroll
        for (int g = 0; g < 4; ++g)
#pragma unroll
          for (int r = 0; r < 4; ++r) {
            const int kg = kbase + g * 16 + l4 * 4 + r;
            const float s0 = (kg <= qrow) ? sc[g][r] : -1e9f;
            sv[g * 4 + r] = s0;
            pmax = fmaxf(pmax, s0);
          }
      } else {          // strictly-below-diagonal: no mask needed
#pragma unroll
        for (int g = 0; g < 4; ++g)
#pragma unroll
          for (int r = 0; r < 4; ++r) {
            const float s0 = sc[g][r];
            sv[g * 4 + r] = s0;
            pmax = fmaxf(pmax, s0);
          }
      }
      pmax = fmaxf(pmax, __shfl_xor(pmax, 16));
      pmax = fmaxf(pmax, __shfl_xor(pmax, 32));
      if (!__all(pmax <= mrun + 8.f)) {   // defer-max: rescale only on growth
        const float mnew = fmaxf(mrun, pmax);
        const float fsc = __expf(mrun - mnew);
        lsum *= fsc;
#pragma unroll
        for (int df = 0; df < 4; ++df) oa[df] *= fsc;
        mrun = mnew;
      }
      float psum = 0.f;
#pragma unroll
      for (int i = 0; i < 16; ++i) { float pv = __expf(sv[i] - mrun); sv[i] = pv; psum += pv; }
      psum += __shfl_xor(psum, 16);
      psum += __shfl_xor(psum, 32);
      lsum += psum;

#pragma unroll
      for (int g = 0; g < 4; ++g) {
        u16x4 pk;
#pragma unroll
        for (int r = 0; r < 4; ++r) pk[r] = f2bf(sv[g * 4 + r]);
        *(u16x4*)(Pw + l15 * 72 + g * 16 + l4 * 4) = pk;
      }
      asm volatile("s_waitcnt lgkmcnt(0)" ::: "memory");
      const u16x8 pf0 = *(const u16x8*)(Pw + l15 * 72 + l4 * 8);
      const u16x8 pf1 = *(const u16x8*)(Pw + l15 * 72 + 32 + l4 * 8);
      __builtin_amdgcn_s_setprio(1);
#pragma unroll
      for (int df = 0; df < 4; ++df) {
        oa[df] = mfma_bf16(vf0[df], pf0, oa[df]);
        oa[df] = mfma_bf16(vf1[df], pf1, oa[df]);
      }
      __builtin_amdgcn_s_setprio(0);
    }
    const float inv = 1.f / lsum;
    u16s* orow = O + ((size_t)qrow * 8 + b) * EMB + h * 64;
#pragma unroll
    for (int df = 0; df < 4; ++df)
#pragma unroll
      for (int r = 0; r < 4; ++r)
        orow[df * 16 + l4 * 4 + r] = f2bf(oa[df][r] * inv);
  }
}

// ---------------- driver ----------------
extern "C" void kernel_launch(void* const* d_in, const int* in_sizes, int n_in,
                              void* d_out, int out_size, void* d_ws, size_t ws_size,
                              hipStream_t stream) {
  const float* x = (const float*)d_in[0];
  const float* z = (const float*)d_in[1];
  const float* wq = (const float*)d_in[2];  const float* bq = (const float*)d_in[3];
  const float* wk = (const float*)d_in[4];  const float* bk = (const float*)d_in[5];
  const float* wv = (const float*)d_in[6];  const float* bv = (const float*)d_in[7];
  const float* wo = (const float*)d_in[8];  const float* bo = (const float*)d_in[9];
  const float* ln1g = (const float*)d_in[10]; const float* ln1b = (const float*)d_in[11];
  const float* pghw = (const float*)d_in[12]; const float* pghb = (const float*)d_in[13];
  const float* pgzw = (const float*)d_in[14]; const float* pgzb = (const float*)d_in[15];
  const float* pvw  = (const float*)d_in[16]; const float* pvb  = (const float*)d_in[17];
  const float* ln2g = (const float*)d_in[18]; const float* ln2b = (const float*)d_in[19];
  const float* fc1w = (const float*)d_in[20]; const float* fc1b = (const float*)d_in[21];
  const float* fc2w = (const float*)d_in[22]; const float* fc2b = (const float*)d_in[23];
  const float* ln3g = (const float*)d_in[24]; const float* ln3b = (const float*)d_in[25];

  char* ws = (char*)d_ws;
  size_t off = 0;
  auto alloc = [&](size_t bytes) -> char* {
    char* p = ws + off;
    off += (bytes + 255) & ~(size_t)255;
    return p;
  };

  u16s* bw_qkv = (u16s*)alloc(2u * 3145728);  // wq|wk|wv concat (3072x1024)
  u16s* bw_o = (u16s*)alloc(2u * 1048576);
  u16s* bw_g = (u16s*)alloc(2u * 1048576);
  u16s* bw_f1 = (u16s*)alloc(2u * 4194304);
  u16s* bw_f2 = (u16s*)alloc(2u * 4194304);
  u16s* xb = (u16s*)alloc(2u * 8388608);
  // qh, kh, vT, attnb are four contiguous 16MB buffers (the QKV3 epilogue
  // relies on qh+8388608 == kh, qh+16777216 == vT); hbuf (8192x4096 bf16 =
  // 64MB) aliases all four. vT is V pre-transposed per head: vT[bh][64][1024].
  u16s* qh = (u16s*)alloc(2u * 8388608);
  u16s* kh = (u16s*)alloc(2u * 8388608);
  u16s* vT = (u16s*)alloc(2u * 8388608);
  u16s* attnb = (u16s*)alloc(2u * 8388608);
  u16s* hbuf = qh;
  u16s* ybufb = (u16s*)alloc(2u * 8388608);   // bf16 pre-LN buffer
  u16s* x1b = (u16s*)alloc(2u * 8388608);     // LN1 output (bf16)
  u16s* x2b = (u16s*)alloc(2u * 8388608);     // LN2 output (bf16)
  float* zgb = (float*)alloc(4u * 8192);
  float* zvb = (float*)alloc(4u * 8192);
  float* bqkv = (float*)alloc(4u * 3072);
  (void)off; (void)ws_size; (void)in_sizes; (void)n_in; (void)out_size;
  (void)kh; (void)vT;

  prep_kernel<<<21504, 256, 0, stream>>>(x, wq, wk, wv, wo, pghw, fc1w, fc2w,
                                         xb, bw_qkv, bw_o, bw_g, bw_f1, bw_f2);
  small_kernel<<<524, 256, 0, stream>>>(z, pgzw, pgzb, pvw, pvb, zgb, zvb,
                                        bq, bk, bv, bqkv);

  // fused QKV projection (N=3072) with head-scatter epilogue
  gemm_nt<EPI_QKV3><<<dim3(24, 64), 256, 0, stream>>>(
      xb, bw_qkv, bqkv, qh, nullptr, nullptr, nullptr, NTOK, 3072, EMB, 0.125f);

  attn_kernel<<<dim3(8, 128), 256, 0, stream>>>(qh, kh, vT, attnb);

  // out-proj + residual(xb) -> ybufb (bf16), then LN1 -> x1b
  gemm_nt<EPI_RES><<<dim3(8, 64), 256, 0, stream>>>(
      attnb, bw_o, bo, ybufb, xb, nullptr, nullptr, NTOK, EMB, EMB, 1.f);
  ln_kernel<0><<<NTOK, 256, 0, stream>>>(ybufb, ln1g, ln1b, x1b, nullptr);

  // gated fusion (residual x1b) -> ybufb, then LN2 -> x2b
  gemm_nt<EPI_GATE><<<dim3(8, 64), 256, 0, stream>>>(
      x1b, bw_g, pghb, ybufb, x1b, zgb, zvb, NTOK, EMB, EMB, 1.f);
  ln_kernel<0><<<NTOK, 256, 0, stream>>>(ybufb, ln2g, ln2b, x2b, nullptr);

  // FFN (residual x2b) -> ybufb, then LN3 -> d_out (f32)
  gemm_nt<EPI_RELU><<<dim3(32, 64), 256, 0, stream>>>(
      x2b, bw_f1, fc1b, hbuf, nullptr, nullptr, nullptr, NTOK, FDIM, EMB, 1.f);
  gemm_nt<EPI_RES><<<dim3(8, 64), 256, 0, stream>>>(
      hbuf, bw_f2, fc2b, ybufb, x2b, nullptr, nullptr, NTOK, EMB, FDIM, 1.f);
  ln_kernel<1><<<NTOK, 256, 0, stream>>>(ybufb, ln3g, ln3b, nullptr, (float*)d_out);
}